// Round 8
// baseline (512.435 us; speedup 1.0000x reference)
//
#include <hip/hip_runtime.h>
#include <hip/hip_bf16.h>
#include <math.h>

#define IN_CHN 128
#define OUT_CHN 128
#define KD 192
#define TM 32                  // edges per tile

typedef __bf16 bf16x8 __attribute__((ext_vector_type(8)));
typedef float f32x4 __attribute__((ext_vector_type(4)));

static __device__ __forceinline__ unsigned short f2b(float f) {
    return __builtin_bit_cast(unsigned short, (__bf16)f);   // RNE
}
static __device__ __forceinline__ float b2f(unsigned short b) {
    return __uint_as_float(((unsigned int)b) << 16);
}
static __device__ __forceinline__ float fast_tanh(float x) {
    float e = __expf(2.0f * x);
    return 1.0f - 2.0f * __builtin_amdgcn_rcpf(e + 1.0f);
}

// async global->LDS, 16B per lane; LDS dest wave-uniform base + lane*16
#define GLL16(gsrc, ldst) \
    __builtin_amdgcn_global_load_lds( \
        (const __attribute__((address_space(1))) unsigned int*)(gsrc), \
        (__attribute__((address_space(3))) unsigned int*)(ldst), 16, 0, 0)

// light barrier: cross-wave LDS visibility WITHOUT draining vmcnt (keeps
// in-flight global_load_lds alive across it)
#define LDS_BARRIER() do { \
    asm volatile("s_waitcnt lgkmcnt(0)" ::: "memory"); \
    __builtin_amdgcn_s_barrier(); \
    __builtin_amdgcn_sched_barrier(0); \
} while (0)

// ---------------- x -> bf16 pre-conversion ----------------

__global__ __launch_bounds__(256) void cvt_x(const float* __restrict__ x,
    unsigned short* __restrict__ xb, long long n8)
{
    long long i = (long long)blockIdx.x * 256 + threadIdx.x;
    if (i >= n8) return;
    const float4* src = (const float4*)(x + i * 8);
    float4 v0 = src[0], v1 = src[1];
    ushort4 p0 = { f2b(v0.x), f2b(v0.y), f2b(v0.z), f2b(v0.w) };
    ushort4 p1 = { f2b(v1.x), f2b(v1.y), f2b(v1.z), f2b(v1.w) };
    *(ushort4*)(xb + i * 8)     = p0;
    *(ushort4*)(xb + i * 8 + 4) = p1;
}

// ---------------- CSR build ----------------

__global__ __launch_bounds__(256) void count_deg(const int* __restrict__ ei,
                                                 int* __restrict__ deg, int E) {
    int e = blockIdx.x * 256 + threadIdx.x;
    if (e < E) atomicAdd(&deg[ei[E + e]], 1);
}

static __device__ __forceinline__ int wave_incl_scan(int v, int lane) {
    #pragma unroll
    for (int off = 1; off < 64; off <<= 1) {
        int t = __shfl_up(v, off);
        if (lane >= off) v += t;
    }
    return v;
}

__global__ __launch_bounds__(256) void scan_local(const int* __restrict__ deg,
    int* __restrict__ offs, int* __restrict__ partial, int Nn)
{
    __shared__ int wsum[4];
    int tid = threadIdx.x, lane = tid & 63, wid = tid >> 6;
    int i = blockIdx.x * 256 + tid;
    int v = (i < Nn) ? deg[i] : 0;
    int incl = wave_incl_scan(v, lane);
    if (lane == 63) wsum[wid] = incl;
    __syncthreads();
    int wpre = 0;
    for (int w = 0; w < wid; ++w) wpre += wsum[w];
    if (i < Nn) offs[i] = wpre + incl - v;
    if (tid == 255) partial[blockIdx.x] = wpre + incl;
}

__global__ __launch_bounds__(256) void scan_partial(int* __restrict__ partial, int nparts)
{
    __shared__ int wsum[4];
    int tid = threadIdx.x, lane = tid & 63, wid = tid >> 6;
    int v = (tid < nparts) ? partial[tid] : 0;
    int incl = wave_incl_scan(v, lane);
    if (lane == 63) wsum[wid] = incl;
    __syncthreads();
    int wpre = 0;
    for (int w = 0; w < wid; ++w) wpre += wsum[w];
    if (tid < nparts) partial[tid] = wpre + incl - v;
}

__global__ __launch_bounds__(256) void finalize_offs(int* __restrict__ offs,
    const int* __restrict__ partial, int* __restrict__ cursor, int Nn)
{
    int i = blockIdx.x * 256 + threadIdx.x;
    if (i < Nn) { int o = offs[i] + partial[i >> 8]; offs[i] = o; cursor[i] = o; }
}

// scatter (src, t) into CSR-permuted order as one 8B store
__global__ __launch_bounds__(256) void fill_perm(const int* __restrict__ ei,
    const float* __restrict__ et, int* __restrict__ cursor,
    uint2* __restrict__ mt, int E)
{
    int e = blockIdx.x * 256 + threadIdx.x;
    if (e < E) {
        int d = ei[E + e];
        int pos = atomicAdd(&cursor[d], 1);
        mt[pos] = make_uint2((unsigned)ei[e], __float_as_uint(et[e]));
    }
}

// ---------------- MFMA GEMM + alpha ----------------
// h = tanh([x[src], te(t)] @ W^T + b), alpha = h . attn, edges in CSR order.
// 4 waves/block; tile = 32 edges x 128 ch; W frags in registers; x tile via
// global_load_lds into dbuf LDS (source-side granule swizzle c^row&15);
// te single-buffered (written post-A, consumed post-light-B); alpha wave
// partials to global alpha4[4][Ep], turned into ex = exp(sum) by calc_ex.
// LDS = 16K (xs) + 4K (te) = 20480 B -> 5 blocks/CU @ launch_bounds(256,5).

__device__ __forceinline__ void load_meta(const uint2* __restrict__ mt,
    int tile, int E, int rbase, int g, int trow, int sv[2], float& tsv)
{
    int e0 = tile * TM;
    #pragma unroll
    for (int i = 0; i < 2; ++i) {
        int e = e0 + rbase + i * 4 + g;
        sv[i] = (int)mt[e < E ? e : E - 1].x;
    }
    int el = e0 + trow;
    tsv = __uint_as_float(mt[el < E ? el : E - 1].y);
}

__global__ __launch_bounds__(256, 5) void gemm_mfma(
    const unsigned short* __restrict__ xb, const uint2* __restrict__ mt,
    const float* __restrict__ freqs, const float* __restrict__ lw,
    const float* __restrict__ lb, const float* __restrict__ attn,
    unsigned short* __restrict__ h_p, float* __restrict__ alpha4,
    int E, int Ep, int n_tiles)
{
    __shared__ unsigned short xs[2][TM][128];   // 16 KB x tile (dbuf)
    __shared__ unsigned short te[TM * 64];      //  4 KB te tile (single, swizzled)

    const int tid  = threadIdx.x;
    const int lane = tid & 63;
    const int wv   = tid >> 6;          // wave 0..3
    const int c16  = lane & 15;
    const int g    = lane >> 4;         // 0..3
    const int wbase = wv * 32;          // this wave's channel base
    const int rbase = wv * 8;           // this wave's gll row base
    const int trow = tid >> 3;          // te row 0..31
    const int tpart = tid & 7;          // te part 0..7 (0-3 sin, 4-7 cos)

    // W frags in registers: lane's row(ch) = wbase+nf*16+c16; k = kk*32+g*8+j
    bf16x8 Wf[6][2];
    #pragma unroll
    for (int kk = 0; kk < 6; ++kk)
        #pragma unroll
        for (int nf = 0; nf < 2; ++nf) {
            const float* wp = lw + (size_t)(wbase + nf * 16 + c16) * KD + kk * 32 + g * 8;
            float4 v0 = *(const float4*)wp;
            float4 v1 = *(const float4*)(wp + 4);
            bf16x8 b;
            b[0] = (__bf16)v0.x; b[1] = (__bf16)v0.y; b[2] = (__bf16)v0.z; b[3] = (__bf16)v0.w;
            b[4] = (__bf16)v1.x; b[5] = (__bf16)v1.y; b[6] = (__bf16)v1.z; b[7] = (__bf16)v1.w;
            Wf[kk][nf] = b;
        }

    f32x4 bias_v[2], attn_v[2];
    #pragma unroll
    for (int nf = 0; nf < 2; ++nf) {
        bias_v[nf] = *(const f32x4*)(lb   + wbase + nf * 16 + g * 4);
        attn_v[nf] = *(const f32x4*)(attn + wbase + nf * 16 + g * 4);
    }

    // this thread's 8 te frequencies (pre-scaled by 2*pi) + sin/cos phase
    const float coff = (tpart >= 4) ? 1.5707963267948966f : 0.0f;  // cos = sin(x+pi/2)
    float frv[8];
    #pragma unroll
    for (int j = 0; j < 8; ++j) frv[j] = freqs[(tpart & 3) * 8 + j] * 6.283185307179586f;

    const int stride = gridDim.x;
    float ts_cur, ts_nxt;
    int sv_nxt[2];

    // ---- prologue: meta(t0), gll(t0) -> xs[0], meta(t1) ----
    {
        int sv0[2];
        load_meta(mt, blockIdx.x, E, rbase, g, trow, sv0, ts_cur);
        #pragma unroll
        for (int i = 0; i < 2; ++i) {
            const int rlo = (rbase + i * 4 + g) & 15;
            const unsigned short* gsrc = xb + (size_t)sv0[i] * IN_CHN + ((c16 ^ rlo) * 8);
            GLL16(gsrc, &xs[0][rbase + i * 4][0]);
        }
        int t1 = blockIdx.x + stride;
        load_meta(mt, t1 < n_tiles ? t1 : n_tiles - 1, E, rbase, g, trow, sv_nxt, ts_nxt);
    }

    int cur = 0;

    for (int tile = blockIdx.x; tile < n_tiles; tile += stride) {
        const int e0 = tile * TM;

        // ---- compute te(t) pack in registers (overlaps gll(t) drain) ----
        ushort4 tp[2];
        {
            float v[8];
            #pragma unroll
            for (int j = 0; j < 8; ++j)
                v[j] = __sinf(ts_cur * frv[j] + coff);
            tp[0] = (ushort4){ f2b(v[0]), f2b(v[1]), f2b(v[2]), f2b(v[3]) };
            tp[1] = (ushort4){ f2b(v[4]), f2b(v[5]), f2b(v[6]), f2b(v[7]) };
        }

        // ---- prefetch meta(t+2) ----
        int sv2[2]; float ts2;
        {
            int t2 = tile + 2 * stride;
            load_meta(mt, t2 < n_tiles ? t2 : n_tiles - 1, E, rbase, g, trow, sv2, ts2);
        }

        __syncthreads();   // A: drains gll(t); all waves done reading xs[cur^1], te(t-1)

        // ---- issue gll(t+1) -> xs[cur^1] (stays in flight through light-B) ----
        if (tile + stride < n_tiles) {
            #pragma unroll
            for (int i = 0; i < 2; ++i) {
                const int rlo = (rbase + i * 4 + g) & 15;
                const unsigned short* gsrc = xb + (size_t)sv_nxt[i] * IN_CHN + ((c16 ^ rlo) * 8);
                GLL16(gsrc, &xs[cur ^ 1][rbase + i * 4][0]);
            }
        }

        // ---- write te(t): row = trow, part = tpart, granule-swizzled ----
        {
            unsigned short* tr = &te[trow * 64];
            int slot = (tpart ^ (trow & 7)) * 8;
            *(ushort4*)(tr + slot)     = tp[0];
            *(ushort4*)(tr + slot + 4) = tp[1];
        }

        LDS_BARRIER();     // B: te visible; gll(t+1) still in flight

        // ---- MFMA: x frags from swizzled LDS, te frags from LDS ----
        f32x4 acc[2][2];
        #pragma unroll
        for (int mi = 0; mi < 2; ++mi) {
            acc[mi][0] = (f32x4){0.f, 0.f, 0.f, 0.f};
            acc[mi][1] = (f32x4){0.f, 0.f, 0.f, 0.f};
        }

        __builtin_amdgcn_s_setprio(1);
        const unsigned short* xsc = &xs[cur][0][0];
        #pragma unroll
        for (int mi = 0; mi < 2; ++mi) {
            const int r = mi * 16 + c16;
            const unsigned short* xrow = xsc + r * 128;
            #pragma unroll
            for (int kk = 0; kk < 4; ++kk) {
                const int slot = ((kk << 2) + g) ^ c16;   // source-swizzled granule
                bf16x8 a = __builtin_bit_cast(bf16x8, *(const uint4*)(xrow + slot * 8));
                acc[mi][0] = __builtin_amdgcn_mfma_f32_16x16x32_bf16(Wf[kk][0], a, acc[mi][0], 0, 0, 0);
                acc[mi][1] = __builtin_amdgcn_mfma_f32_16x16x32_bf16(Wf[kk][1], a, acc[mi][1], 0, 0, 0);
            }
            const unsigned short* trw = &te[r * 64];
            bf16x8 s8 = __builtin_bit_cast(bf16x8, *(const uint4*)(trw + ((g ^ (r & 7)) * 8)));
            bf16x8 c8 = __builtin_bit_cast(bf16x8, *(const uint4*)(trw + (((g + 4) ^ (r & 7)) * 8)));
            acc[mi][0] = __builtin_amdgcn_mfma_f32_16x16x32_bf16(Wf[4][0], s8, acc[mi][0], 0, 0, 0);
            acc[mi][1] = __builtin_amdgcn_mfma_f32_16x16x32_bf16(Wf[4][1], s8, acc[mi][1], 0, 0, 0);
            acc[mi][0] = __builtin_amdgcn_mfma_f32_16x16x32_bf16(Wf[5][0], c8, acc[mi][0], 0, 0, 0);
            acc[mi][1] = __builtin_amdgcn_mfma_f32_16x16x32_bf16(Wf[5][1], c8, acc[mi][1], 0, 0, 0);
        }
        __builtin_amdgcn_s_setprio(0);

        // ---- epilogue: tanh, alpha partial, direct global stores ----
        #pragma unroll
        for (int mi = 0; mi < 2; ++mi) {
            int e = e0 + mi * 16 + c16;
            float p = 0.0f;
            ushort4 pv[2];
            #pragma unroll
            for (int nf = 0; nf < 2; ++nf) {
                f32x4 z = acc[mi][nf];
                #pragma unroll
                for (int r = 0; r < 4; ++r) {
                    float h = fast_tanh(z[r] + bias_v[nf][r]);
                    z[r] = h;
                    p = fmaf(h, attn_v[nf][r], p);
                }
                pv[nf] = (ushort4){ f2b(z[0]), f2b(z[1]), f2b(z[2]), f2b(z[3]) };
            }
            p += __shfl_xor(p, 16);
            p += __shfl_xor(p, 32);
            if (e < E) {
                unsigned short* hp = h_p + (size_t)e * OUT_CHN + wbase + g * 4;
                *(ushort4*)hp        = pv[0];
                *(ushort4*)(hp + 16) = pv[1];
                if (g == 0) alpha4[(size_t)wv * Ep + e] = p;
            }
        }

        ts_cur = ts_nxt; ts_nxt = ts2;
        sv_nxt[0] = sv2[0]; sv_nxt[1] = sv2[1];
        cur ^= 1;
    }
}

// ---------------- ex = exp(sum of alpha planes) ----------------
// |alpha| <= sum|attn| ~ 14 -> exp safe in fp32 without max subtraction;
// weights ex/sum(ex) are mathematically identical to the max-shifted form.

__global__ __launch_bounds__(256) void calc_ex(const float* __restrict__ a4,
    float* __restrict__ ex, int E, int Ep)
{
    int i = blockIdx.x * 256 + threadIdx.x;   // float4 index
    int e = i * 4;
    if (e + 3 < E) {
        float4 v0 = *(const float4*)(a4 + e);
        float4 v1 = *(const float4*)(a4 + Ep + e);
        float4 v2 = *(const float4*)(a4 + 2 * (size_t)Ep + e);
        float4 v3 = *(const float4*)(a4 + 3 * (size_t)Ep + e);
        float4 r = { __expf(v0.x + v1.x + v2.x + v3.x),
                     __expf(v0.y + v1.y + v2.y + v3.y),
                     __expf(v0.z + v1.z + v2.z + v3.z),
                     __expf(v0.w + v1.w + v2.w + v3.w) };
        *(float4*)(ex + e) = r;
    } else {
        for (int q = e; q < E; ++q)
            ex[q] = __expf(a4[q] + a4[Ep + q] + a4[2 * (size_t)Ep + q] + a4[3 * (size_t)Ep + q]);
    }
}

// ---------------- per-node aggregation (one wave per node, 2 passes) ----------------

__global__ __launch_bounds__(256) void agg(
    const unsigned short* __restrict__ h_p, const float* __restrict__ ex,
    const int* __restrict__ offs, const int* __restrict__ deg,
    float* __restrict__ out, int Nn)
{
    int wid  = threadIdx.x >> 6;
    int lane = threadIdx.x & 63;
    int node = blockIdx.x * 4 + wid;
    if (node >= Nn) return;
    int start = offs[node];
    int d = deg[node];
    int sub = lane >> 4;            // 0..3
    int ch  = (lane & 15) * 8;      // 8 channels per lane
    float4* op = (float4*)(out + (size_t)node * OUT_CHN + ch);
    if (d == 0) {
        if (sub == 0) { op[0] = (float4){0,0,0,0}; op[1] = (float4){0,0,0,0}; }
        return;
    }

    // pass 1: denom = sum of ex (no max pass needed: ex bounded ~1e6)
    float s = 0.0f;
    for (int i = lane; i < d; i += 64) s += ex[start + i];
    #pragma unroll
    for (int off = 32; off > 0; off >>= 1) s += __shfl_xor(s, off);
    float rs = __builtin_amdgcn_rcpf(s + 1e-16f);

    // pass 2: weighted sum of h rows, 4 edges/iter
    float a[8];
    #pragma unroll
    for (int q = 0; q < 8; ++q) a[q] = 0.0f;

    for (int i = 0; i < d; i += 4) {
        int idx = i + sub;
        float w = 0.0f;
        uint4 hv = {0u, 0u, 0u, 0u};
        if (idx < d) {
            w = ex[start + idx] * rs;
            hv = *(const uint4*)(h_p + (size_t)(start + idx) * OUT_CHN + ch);
        }
        unsigned int hw[4] = { hv.x, hv.y, hv.z, hv.w };
        #pragma unroll
        for (int q = 0; q < 4; ++q) {
            a[2*q]   = fmaf(b2f((unsigned short)(hw[q] & 0xFFFFu)), w, a[2*q]);
            a[2*q+1] = fmaf(b2f((unsigned short)(hw[q] >> 16)),     w, a[2*q+1]);
        }
    }
    #pragma unroll
    for (int q = 0; q < 8; ++q) {
        a[q] += __shfl_xor(a[q], 16);
        a[q] += __shfl_xor(a[q], 32);
    }
    if (sub == 0) {
        op[0] = (float4){a[0], a[1], a[2], a[3]};
        op[1] = (float4){a[4], a[5], a[6], a[7]};
    }
}

// ---------------- launch ----------------

extern "C" void kernel_launch(void* const* d_in, const int* in_sizes, int n_in,
                              void* d_out, int out_size, void* d_ws, size_t ws_size,
                              hipStream_t stream) {
    const float* x     = (const float*)d_in[0];
    const int*   ei    = (const int*)d_in[1];     // [2, E]
    const float* et    = (const float*)d_in[2];
    const float* freqs = (const float*)d_in[3];
    const float* lw    = (const float*)d_in[4];   // [128, 192]
    const float* lb    = (const float*)d_in[5];
    const float* attn  = (const float*)d_in[6];
    float* out = (float*)d_out;

    const int E  = in_sizes[2];
    const int Nn = in_sizes[0] / IN_CHN;
    const int Ep = (E + 3) & ~3;

    // workspace layout
    char* ws = (char*)d_ws;
    unsigned short* h_p = (unsigned short*)ws;                // E*128 bf16 (perm order)
    size_t off = (size_t)E * OUT_CHN * sizeof(unsigned short);
    float* ex      = (float*)(ws + off); off += (size_t)Ep * sizeof(float);
    float* alpha4  = (float*)(ws + off); off += (size_t)Ep * 4 * sizeof(float);
    uint2* mt      = (uint2*)(ws + off); off += (size_t)E * sizeof(uint2);
    unsigned short* xb = (unsigned short*)(ws + off); off += (size_t)Nn * IN_CHN * sizeof(unsigned short);
    int*   deg     = (int*)(ws + off);   off += (size_t)Nn * sizeof(int);
    int*   offs    = (int*)(ws + off);   off += (size_t)Nn * sizeof(int);
    int*   cursor  = (int*)(ws + off);   off += (size_t)Nn * sizeof(int);
    int*   partial = (int*)(ws + off);

    const int nblk = (Nn + 255) / 256;
    const int eblk = (E + 255) / 256;

    long long n8 = (long long)Nn * IN_CHN / 8;
    cvt_x<<<(unsigned)((n8 + 255) / 256), 256, 0, stream>>>(x, xb, n8);

    hipMemsetAsync(deg, 0, (size_t)Nn * sizeof(int), stream);
    count_deg<<<eblk, 256, 0, stream>>>(ei, deg, E);
    scan_local<<<nblk, 256, 0, stream>>>(deg, offs, partial, Nn);
    scan_partial<<<1, 256, 0, stream>>>(partial, nblk);
    finalize_offs<<<nblk, 256, 0, stream>>>(offs, partial, cursor, Nn);
    fill_perm<<<eblk, 256, 0, stream>>>(ei, et, cursor, mt, E);

    const int n_tiles = (E + TM - 1) / TM;
    gemm_mfma<<<1280, 256, 0, stream>>>(xb, mt, freqs, lw, lb, attn,
                                        h_p, alpha4, E, Ep, n_tiles);

    calc_ex<<<(Ep / 4 + 255) / 256, 256, 0, stream>>>(alpha4, ex, E, Ep);

    agg<<<(Nn + 3) / 4, 256, 0, stream>>>(h_p, ex, offs, deg, out, Nn);
}

// Round 9
// 253.967 us; speedup vs baseline: 2.0177x; 2.0177x over previous
//
#include <hip/hip_runtime.h>
#include <hip/hip_bf16.h>
#include <math.h>

#define IN_CHN 128
#define OUT_CHN 128
#define KD 192
#define TM 64                  // edges per tile

typedef __bf16 bf16x8 __attribute__((ext_vector_type(8)));
typedef float f32x4 __attribute__((ext_vector_type(4)));

static __device__ __forceinline__ unsigned short f2b(float f) {
    return __builtin_bit_cast(unsigned short, (__bf16)f);   // RNE
}
static __device__ __forceinline__ float b2f(unsigned short b) {
    return __uint_as_float(((unsigned int)b) << 16);
}
static __device__ __forceinline__ float fast_tanh(float x) {
    float e = __expf(2.0f * x);
    return 1.0f - 2.0f * __builtin_amdgcn_rcpf(e + 1.0f);
}

// async global->LDS, 16B per lane; LDS dest wave-uniform base + lane*16
#define GLL16(gsrc, ldst) \
    __builtin_amdgcn_global_load_lds( \
        (const __attribute__((address_space(1))) unsigned int*)(gsrc), \
        (__attribute__((address_space(3))) unsigned int*)(ldst), 16, 0, 0)

// light barrier: cross-wave LDS visibility WITHOUT draining vmcnt (keeps
// in-flight global_load_lds alive across it)
#define LDS_BARRIER() do { \
    asm volatile("s_waitcnt lgkmcnt(0)" ::: "memory"); \
    __builtin_amdgcn_s_barrier(); \
    __builtin_amdgcn_sched_barrier(0); \
} while (0)

// ---------------- x -> bf16 pre-conversion ----------------

__global__ __launch_bounds__(256) void cvt_x(const float* __restrict__ x,
    unsigned short* __restrict__ xb, long long n8)
{
    long long i = (long long)blockIdx.x * 256 + threadIdx.x;
    if (i >= n8) return;
    const float4* src = (const float4*)(x + i * 8);
    float4 v0 = src[0], v1 = src[1];
    ushort4 p0 = { f2b(v0.x), f2b(v0.y), f2b(v0.z), f2b(v0.w) };
    ushort4 p1 = { f2b(v1.x), f2b(v1.y), f2b(v1.z), f2b(v1.w) };
    *(ushort4*)(xb + i * 8)     = p0;
    *(ushort4*)(xb + i * 8 + 4) = p1;
}

// ---------------- CSR build ----------------

__global__ __launch_bounds__(256) void count_deg(const int* __restrict__ ei,
                                                 int* __restrict__ deg, int E) {
    int e = blockIdx.x * 256 + threadIdx.x;
    if (e < E) atomicAdd(&deg[ei[E + e]], 1);
}

static __device__ __forceinline__ int wave_incl_scan(int v, int lane) {
    #pragma unroll
    for (int off = 1; off < 64; off <<= 1) {
        int t = __shfl_up(v, off);
        if (lane >= off) v += t;
    }
    return v;
}

__global__ __launch_bounds__(256) void scan_local(const int* __restrict__ deg,
    int* __restrict__ offs, int* __restrict__ partial, int Nn)
{
    __shared__ int wsum[4];
    int tid = threadIdx.x, lane = tid & 63, wid = tid >> 6;
    int i = blockIdx.x * 256 + tid;
    int v = (i < Nn) ? deg[i] : 0;
    int incl = wave_incl_scan(v, lane);
    if (lane == 63) wsum[wid] = incl;
    __syncthreads();
    int wpre = 0;
    for (int w = 0; w < wid; ++w) wpre += wsum[w];
    if (i < Nn) offs[i] = wpre + incl - v;
    if (tid == 255) partial[blockIdx.x] = wpre + incl;
}

__global__ __launch_bounds__(256) void scan_partial(int* __restrict__ partial, int nparts)
{
    __shared__ int wsum[4];
    int tid = threadIdx.x, lane = tid & 63, wid = tid >> 6;
    int v = (tid < nparts) ? partial[tid] : 0;
    int incl = wave_incl_scan(v, lane);
    if (lane == 63) wsum[wid] = incl;
    __syncthreads();
    int wpre = 0;
    for (int w = 0; w < wid; ++w) wpre += wsum[w];
    if (tid < nparts) partial[tid] = wpre + incl - v;
}

__global__ __launch_bounds__(256) void finalize_offs(int* __restrict__ offs,
    const int* __restrict__ partial, int* __restrict__ cursor, int Nn)
{
    int i = blockIdx.x * 256 + threadIdx.x;
    if (i < Nn) { int o = offs[i] + partial[i >> 8]; offs[i] = o; cursor[i] = o; }
}

// scatter (src, t) into CSR-permuted order as one 8B store
__global__ __launch_bounds__(256) void fill_perm(const int* __restrict__ ei,
    const float* __restrict__ et, int* __restrict__ cursor,
    uint2* __restrict__ mt, int E)
{
    int e = blockIdx.x * 256 + threadIdx.x;
    if (e < E) {
        int d = ei[E + e];
        int pos = atomicAdd(&cursor[d], 1);
        mt[pos] = make_uint2((unsigned)ei[e], __float_as_uint(et[e]));
    }
}

// ---------------- MFMA GEMM + alpha ----------------
// h = tanh([x[src], te(t)] @ W^T + b), alpha = h . attn, edges in CSR order.
// 8 waves/block (512 thr); wave owns 16 output channels -> Wf = 24 VGPR/lane.
// Tile = 64 edges x 128 ch; x tile via global_load_lds into dbuf LDS
// (source-side granule swizzle c^row&15); te single-buffered (written
// post-A, consumed post-light-B). Each wave stores its own alpha partial
// plane alpha8[wv][e] -> no cross-wave reduce in-kernel.
// LDS = 32K (xs) + 8K (te) = 40960 B; VGPR ~80 -> 3 blocks/CU = 24 waves.

__device__ __forceinline__ void load_meta(const uint2* __restrict__ mt,
    int tile, int E, int rbase, int g, int trow, int sv[2], float& tsv)
{
    int e0 = tile * TM;
    #pragma unroll
    for (int i = 0; i < 2; ++i) {
        int e = e0 + rbase + i * 4 + g;
        sv[i] = (int)mt[e < E ? e : E - 1].x;
    }
    int el = e0 + trow;
    tsv = __uint_as_float(mt[el < E ? el : E - 1].y);
}

__global__ __launch_bounds__(512) void gemm_mfma(
    const unsigned short* __restrict__ xb, const uint2* __restrict__ mt,
    const float* __restrict__ freqs, const float* __restrict__ lw,
    const float* __restrict__ lb, const float* __restrict__ attn,
    unsigned short* __restrict__ h_p, float* __restrict__ alpha8,
    int E, int Ep, int n_tiles)
{
    __shared__ unsigned short xs[2][TM][128];   // 32 KB x tile (dbuf)
    __shared__ unsigned short te[TM * 64];      //  8 KB te tile (single, swizzled)

    const int tid  = threadIdx.x;
    const int lane = tid & 63;
    const int wv   = tid >> 6;          // wave 0..7
    const int c16  = lane & 15;
    const int g    = lane >> 4;         // 0..3
    const int wbase = wv * 16;          // this wave's channel base
    const int rbase = wv * 8;           // this wave's gll row base
    const int trow  = tid >> 3;         // te row 0..63
    const int tpart = tid & 7;          // te part 0..7 (0-3 sin, 4-7 cos)

    // W frags in registers: lane's row(ch) = wbase+c16; k = kk*32+g*8+j
    bf16x8 Wf[6];
    #pragma unroll
    for (int kk = 0; kk < 6; ++kk) {
        const float* wp = lw + (size_t)(wbase + c16) * KD + kk * 32 + g * 8;
        float4 v0 = *(const float4*)wp;
        float4 v1 = *(const float4*)(wp + 4);
        bf16x8 b;
        b[0] = (__bf16)v0.x; b[1] = (__bf16)v0.y; b[2] = (__bf16)v0.z; b[3] = (__bf16)v0.w;
        b[4] = (__bf16)v1.x; b[5] = (__bf16)v1.y; b[6] = (__bf16)v1.z; b[7] = (__bf16)v1.w;
        Wf[kk] = b;
    }

    // bias/attn for this lane's output channels: wbase + g*4 + r
    const f32x4 bias_v = *(const f32x4*)(lb   + wbase + g * 4);
    const f32x4 attn_v = *(const f32x4*)(attn + wbase + g * 4);

    // this thread's 8 te frequencies (pre-scaled by 2*pi) + sin/cos phase
    const float coff = (tpart >= 4) ? 1.5707963267948966f : 0.0f;  // cos = sin(x+pi/2)
    float frv[8];
    #pragma unroll
    for (int j = 0; j < 8; ++j) frv[j] = freqs[(tpart & 3) * 8 + j] * 6.283185307179586f;

    const int stride = gridDim.x;
    float ts_cur, ts_nxt;
    int sv_nxt[2];

    // ---- prologue: meta(t0), gll(t0) -> xs[0], meta(t1) ----
    {
        int sv0[2];
        load_meta(mt, blockIdx.x, E, rbase, g, trow, sv0, ts_cur);
        #pragma unroll
        for (int i = 0; i < 2; ++i) {
            const int rlo = (rbase + i * 4 + g) & 15;
            const unsigned short* gsrc = xb + (size_t)sv0[i] * IN_CHN + ((c16 ^ rlo) * 8);
            GLL16(gsrc, &xs[0][rbase + i * 4][0]);
        }
        int t1 = blockIdx.x + stride;
        load_meta(mt, t1 < n_tiles ? t1 : n_tiles - 1, E, rbase, g, trow, sv_nxt, ts_nxt);
    }

    int cur = 0;

    for (int tile = blockIdx.x; tile < n_tiles; tile += stride) {
        const int e0 = tile * TM;

        // ---- compute te(t) pack in registers (overlaps gll(t) drain) ----
        ushort4 tp[2];
        {
            float v[8];
            #pragma unroll
            for (int j = 0; j < 8; ++j)
                v[j] = __sinf(ts_cur * frv[j] + coff);
            tp[0] = (ushort4){ f2b(v[0]), f2b(v[1]), f2b(v[2]), f2b(v[3]) };
            tp[1] = (ushort4){ f2b(v[4]), f2b(v[5]), f2b(v[6]), f2b(v[7]) };
        }

        // ---- prefetch meta(t+2) ----
        int sv2[2]; float ts2;
        {
            int t2 = tile + 2 * stride;
            load_meta(mt, t2 < n_tiles ? t2 : n_tiles - 1, E, rbase, g, trow, sv2, ts2);
        }

        __syncthreads();   // A: drains gll(t); all waves done reading xs[cur^1], te(t-1)

        // ---- issue gll(t+1) -> xs[cur^1] (stays in flight through light-B) ----
        if (tile + stride < n_tiles) {
            #pragma unroll
            for (int i = 0; i < 2; ++i) {
                const int rlo = (rbase + i * 4 + g) & 15;
                const unsigned short* gsrc = xb + (size_t)sv_nxt[i] * IN_CHN + ((c16 ^ rlo) * 8);
                GLL16(gsrc, &xs[cur ^ 1][rbase + i * 4][0]);
            }
        }

        // ---- write te(t): row = trow, part = tpart, granule-swizzled ----
        {
            unsigned short* tr = &te[trow * 64];
            int slot = (tpart ^ (trow & 7)) * 8;
            *(ushort4*)(tr + slot)     = tp[0];
            *(ushort4*)(tr + slot + 4) = tp[1];
        }

        LDS_BARRIER();     // B: te visible; gll(t+1) still in flight

        // ---- MFMA: x frags from swizzled LDS, te frags from LDS ----
        f32x4 acc[4];
        #pragma unroll
        for (int mi = 0; mi < 4; ++mi) acc[mi] = (f32x4){0.f, 0.f, 0.f, 0.f};

        __builtin_amdgcn_s_setprio(1);
        const unsigned short* xsc = &xs[cur][0][0];
        #pragma unroll
        for (int mi = 0; mi < 4; ++mi) {
            const int r = mi * 16 + c16;
            const unsigned short* xrow = xsc + r * 128;
            #pragma unroll
            for (int kk = 0; kk < 4; ++kk) {
                const int slot = ((kk << 2) + g) ^ c16;   // source-swizzled granule
                bf16x8 a = __builtin_bit_cast(bf16x8, *(const uint4*)(xrow + slot * 8));
                acc[mi] = __builtin_amdgcn_mfma_f32_16x16x32_bf16(Wf[kk], a, acc[mi], 0, 0, 0);
            }
            const unsigned short* trw = &te[r * 64];
            bf16x8 s8 = __builtin_bit_cast(bf16x8, *(const uint4*)(trw + ((g ^ (r & 7)) * 8)));
            bf16x8 c8 = __builtin_bit_cast(bf16x8, *(const uint4*)(trw + (((g + 4) ^ (r & 7)) * 8)));
            acc[mi] = __builtin_amdgcn_mfma_f32_16x16x32_bf16(Wf[4], s8, acc[mi], 0, 0, 0);
            acc[mi] = __builtin_amdgcn_mfma_f32_16x16x32_bf16(Wf[5], c8, acc[mi], 0, 0, 0);
        }
        __builtin_amdgcn_s_setprio(0);

        // ---- epilogue: tanh, alpha partial (own plane), direct global stores ----
        #pragma unroll
        for (int mi = 0; mi < 4; ++mi) {
            int e = e0 + mi * 16 + c16;
            f32x4 z = acc[mi];
            float p = 0.0f;
            #pragma unroll
            for (int r = 0; r < 4; ++r) {
                float h = fast_tanh(z[r] + bias_v[r]);
                z[r] = h;
                p = fmaf(h, attn_v[r], p);
            }
            ushort4 pv = (ushort4){ f2b(z[0]), f2b(z[1]), f2b(z[2]), f2b(z[3]) };
            p += __shfl_xor(p, 16);
            p += __shfl_xor(p, 32);
            if (e < E) {
                *(ushort4*)(h_p + (size_t)e * OUT_CHN + wbase + g * 4) = pv;
                if (g == 0) alpha8[(size_t)wv * Ep + e] = p;
            }
        }

        ts_cur = ts_nxt; ts_nxt = ts2;
        sv_nxt[0] = sv2[0]; sv_nxt[1] = sv2[1];
        cur ^= 1;
    }
}

// ---------------- ex = exp(sum of 8 alpha planes), in-place into plane 0 ----
// |alpha| <= sum|attn| ~ 14 -> exp safe in fp32 without max subtraction;
// weights ex/sum(ex) are mathematically identical to the max-shifted form.

__global__ __launch_bounds__(256) void calc_ex(float* __restrict__ a8,
    int E, int Ep)
{
    int i = blockIdx.x * 256 + threadIdx.x;   // float4 index
    int e = i * 4;
    if (e + 3 < E) {
        float4 s = *(const float4*)(a8 + e);
        #pragma unroll
        for (int q = 1; q < 8; ++q) {
            float4 v = *(const float4*)(a8 + (size_t)q * Ep + e);
            s.x += v.x; s.y += v.y; s.z += v.z; s.w += v.w;
        }
        float4 r = { __expf(s.x), __expf(s.y), __expf(s.z), __expf(s.w) };
        *(float4*)(a8 + e) = r;
    } else {
        for (int q = e; q < E; ++q) {
            float s = a8[q];
            for (int p = 1; p < 8; ++p) s += a8[(size_t)p * Ep + q];
            a8[q] = __expf(s);
        }
    }
}

// ---------------- per-node aggregation (one wave per node, 2 passes) ----------------

__global__ __launch_bounds__(256) void agg(
    const unsigned short* __restrict__ h_p, const float* __restrict__ ex,
    const int* __restrict__ offs, const int* __restrict__ deg,
    float* __restrict__ out, int Nn)
{
    int wid  = threadIdx.x >> 6;
    int lane = threadIdx.x & 63;
    int node = blockIdx.x * 4 + wid;
    if (node >= Nn) return;
    int start = offs[node];
    int d = deg[node];
    int sub = lane >> 4;            // 0..3
    int ch  = (lane & 15) * 8;      // 8 channels per lane
    float4* op = (float4*)(out + (size_t)node * OUT_CHN + ch);
    if (d == 0) {
        if (sub == 0) { op[0] = (float4){0,0,0,0}; op[1] = (float4){0,0,0,0}; }
        return;
    }

    // pass 1: denom = sum of ex
    float s = 0.0f;
    for (int i = lane; i < d; i += 64) s += ex[start + i];
    #pragma unroll
    for (int off = 32; off > 0; off >>= 1) s += __shfl_xor(s, off);
    float rs = __builtin_amdgcn_rcpf(s + 1e-16f);

    // pass 2: weighted sum of h rows, 4 edges/iter
    float a[8];
    #pragma unroll
    for (int q = 0; q < 8; ++q) a[q] = 0.0f;

    for (int i = 0; i < d; i += 4) {
        int idx = i + sub;
        float w = 0.0f;
        uint4 hv = {0u, 0u, 0u, 0u};
        if (idx < d) {
            w = ex[start + idx] * rs;
            hv = *(const uint4*)(h_p + (size_t)(start + idx) * OUT_CHN + ch);
        }
        unsigned int hw[4] = { hv.x, hv.y, hv.z, hv.w };
        #pragma unroll
        for (int q = 0; q < 4; ++q) {
            a[2*q]   = fmaf(b2f((unsigned short)(hw[q] & 0xFFFFu)), w, a[2*q]);
            a[2*q+1] = fmaf(b2f((unsigned short)(hw[q] >> 16)),     w, a[2*q+1]);
        }
    }
    #pragma unroll
    for (int q = 0; q < 8; ++q) {
        a[q] += __shfl_xor(a[q], 16);
        a[q] += __shfl_xor(a[q], 32);
    }
    if (sub == 0) {
        op[0] = (float4){a[0], a[1], a[2], a[3]};
        op[1] = (float4){a[4], a[5], a[6], a[7]};
    }
}

// ---------------- launch ----------------

extern "C" void kernel_launch(void* const* d_in, const int* in_sizes, int n_in,
                              void* d_out, int out_size, void* d_ws, size_t ws_size,
                              hipStream_t stream) {
    const float* x     = (const float*)d_in[0];
    const int*   ei    = (const int*)d_in[1];     // [2, E]
    const float* et    = (const float*)d_in[2];
    const float* freqs = (const float*)d_in[3];
    const float* lw    = (const float*)d_in[4];   // [128, 192]
    const float* lb    = (const float*)d_in[5];
    const float* attn  = (const float*)d_in[6];
    float* out = (float*)d_out;

    const int E  = in_sizes[2];
    const int Nn = in_sizes[0] / IN_CHN;
    const int Ep = (E + 3) & ~3;

    // workspace layout
    char* ws = (char*)d_ws;
    unsigned short* h_p = (unsigned short*)ws;                // E*128 bf16 (perm order)
    size_t off = (size_t)E * OUT_CHN * sizeof(unsigned short);
    float* alpha8  = (float*)(ws + off); off += (size_t)Ep * 8 * sizeof(float);  // ex = plane 0 after calc_ex
    uint2* mt      = (uint2*)(ws + off); off += (size_t)E * sizeof(uint2);
    unsigned short* xb = (unsigned short*)(ws + off); off += (size_t)Nn * IN_CHN * sizeof(unsigned short);
    int*   deg     = (int*)(ws + off);   off += (size_t)Nn * sizeof(int);
    int*   offs    = (int*)(ws + off);   off += (size_t)Nn * sizeof(int);
    int*   cursor  = (int*)(ws + off);   off += (size_t)Nn * sizeof(int);
    int*   partial = (int*)(ws + off);

    const int nblk = (Nn + 255) / 256;
    const int eblk = (E + 255) / 256;

    long long n8 = (long long)Nn * IN_CHN / 8;
    cvt_x<<<(unsigned)((n8 + 255) / 256), 256, 0, stream>>>(x, xb, n8);

    hipMemsetAsync(deg, 0, (size_t)Nn * sizeof(int), stream);
    count_deg<<<eblk, 256, 0, stream>>>(ei, deg, E);
    scan_local<<<nblk, 256, 0, stream>>>(deg, offs, partial, Nn);
    scan_partial<<<1, 256, 0, stream>>>(partial, nblk);
    finalize_offs<<<nblk, 256, 0, stream>>>(offs, partial, cursor, Nn);
    fill_perm<<<eblk, 256, 0, stream>>>(ei, et, cursor, mt, E);

    const int n_tiles = (E + TM - 1) / TM;
    gemm_mfma<<<768, 512, 0, stream>>>(xb, mt, freqs, lw, lb, attn,
                                       h_p, alpha8, E, Ep, n_tiles);

    calc_ex<<<(Ep / 4 + 255) / 256, 256, 0, stream>>>(alpha8, E, Ep);

    agg<<<(Nn + 3) / 4, 256, 0, stream>>>(h_p, alpha8, offs, deg, out, Nn);
}